// Round 1
// baseline (262.662 us; speedup 1.0000x reference)
//
#include <hip/hip_runtime.h>
#include <hip/hip_fp16.h>

typedef _Float16 f16;
typedef _Float16 f16x8 __attribute__((ext_vector_type(8)));
typedef _Float16 f16x4 __attribute__((ext_vector_type(4)));
typedef float f32x4 __attribute__((ext_vector_type(4)));

#define GLB(p) ((const __attribute__((address_space(1))) void*)(p))
#define LDSP(p) ((__attribute__((address_space(3))) void*)(p))

__device__ __forceinline__ void gload16(const void* g, void* l) {
  __builtin_amdgcn_global_load_lds(GLB(g), LDSP(l), 16, 0, 0);
}

// ---------------- prep ----------------
__global__ __launch_bounds__(256) void prep_x(const float* __restrict__ x,
                                              f16* __restrict__ xb) {
  int i = (blockIdx.x * 256 + threadIdx.x) * 4;
  float4 v = *(const float4*)(x + i);
  f16x4 o = {(f16)v.x, (f16)v.y, (f16)v.z, (f16)v.w};
  *(f16x4*)(xb + i) = o;
}

// WT'[n'][c] = W[c][(n'&255)*8 + (n'>>8)]   (n' = h*256+d, src n = d*8+h)
// WoT'[dm][n'] = Wo[(d*8+h)*256 + dm]
__global__ __launch_bounds__(256) void prep_w(
    const float* __restrict__ Wq, const float* __restrict__ Wk,
    const float* __restrict__ Wv, const float* __restrict__ Wo,
    const float* __restrict__ bq, const float* __restrict__ bk,
    const float* __restrict__ bv,
    f16* __restrict__ WqT, f16* __restrict__ WkT, f16* __restrict__ WvT,
    f16* __restrict__ WoT, float* __restrict__ bqp, float* __restrict__ bkp,
    float* __restrict__ bvp) {
  int i = blockIdx.x * 256 + threadIdx.x;  // 0..524287
  {
    int np = i >> 8, c = i & 255;
    int src = c * 2048 + (np & 255) * 8 + (np >> 8);
    WqT[i] = (f16)Wq[src];
    WkT[i] = (f16)Wk[src];
    WvT[i] = (f16)Wv[src];
  }
  {
    int dm = i >> 11, np = i & 2047;
    WoT[i] = (f16)Wo[((np & 255) * 8 + (np >> 8)) * 256 + dm];
  }
  if (i < 2048) {
    int src = (i & 255) * 8 + (i >> 8);
    bqp[i] = bq[src];
    bkp[i] = bk[src];
    bvp[i] = bv[src];
  }
}

// ---------------- generic 128x128 fp16 GEMM, K-innermost operands ----------------
// A(m,k) elem = (m>>8)*aq1 + (m&255)*256 + (k>>8)*aq3 + (k&255)
// B(n,k) elem = n*ldb + k
// C(m,n) elem = (m>>8)*cp1 + (m&255)*256 + (n>>8)*cp3 + (n&255)
// OUTMODE: 0 = f16 out + col bias, 1 = f16 out + row bias, 2 = f32 out + col bias
template <int OUTMODE>
__global__ __launch_bounds__(256) void gemm128(
    const f16* __restrict__ A, const f16* __restrict__ B,
    const float* __restrict__ bias, void* __restrict__ Cptr, int K, int aq1,
    int aq3, int ldb, long cp1, long cp3) {
  __shared__ f16 As[2][128 * 32];
  __shared__ f16 Bs[2][128 * 32];
  const int tid = threadIdx.x;
  const int m0 = blockIdx.y * 128;
  const int n0 = blockIdx.x * 128;
  const int lane = tid & 63, wid = tid >> 6;
  const int l15 = lane & 15, lg = lane >> 4;
  const int wm = (wid >> 1) * 64, wn = (wid & 1) * 64;

  f32x4 acc[4][4] = {};

  auto stage = [&](int buf, int kt) {
    int k0 = kt * 32;
#pragma unroll
    for (int r = 0; r < 2; ++r) {
      int flat = r * 4096 + tid * 16;  // byte offset within 8KB tile
      int row = flat >> 6;             // 64B per row
      int kk = k0 + ((flat & 63) >> 1);
      int m = m0 + row;
      gload16(A + (long)(m >> 8) * aq1 + (long)(m & 255) * 256 +
                  (long)(kk >> 8) * aq3 + (kk & 255),
              (char*)(&As[buf][0]) + flat);
      int n = n0 + row;
      gload16(B + (long)n * ldb + kk, (char*)(&Bs[buf][0]) + flat);
    }
  };

  const int T = K >> 5;
  stage(0, 0);
  for (int t = 0; t < T; ++t) {
    __syncthreads();  // staged buf[t&1] visible; all reads of buf[(t+1)&1] done
    if (t + 1 < T) stage((t + 1) & 1, t + 1);
    const f16* as = &As[t & 1][0];
    const f16* bs = &Bs[t & 1][0];
    f16x8 af[4], bf[4];
#pragma unroll
    for (int i = 0; i < 4; ++i)
      af[i] = *(const f16x8*)(as + (wm + i * 16 + l15) * 32 + lg * 8);
#pragma unroll
    for (int j = 0; j < 4; ++j)
      bf[j] = *(const f16x8*)(bs + (wn + j * 16 + l15) * 32 + lg * 8);
#pragma unroll
    for (int i = 0; i < 4; ++i)
#pragma unroll
      for (int j = 0; j < 4; ++j)
        acc[i][j] =
            __builtin_amdgcn_mfma_f32_16x16x32_f16(af[i], bf[j], acc[i][j], 0, 0, 0);
  }

#pragma unroll
  for (int i = 0; i < 4; ++i) {
#pragma unroll
    for (int j = 0; j < 4; ++j) {
#pragma unroll
      for (int jj = 0; jj < 4; ++jj) {
        int m = m0 + wm + i * 16 + lg * 4 + jj;
        int n = n0 + wn + j * 16 + l15;
        float v = acc[i][j][jj];
        v += (OUTMODE == 1) ? bias[m] : bias[n];
        long off = (long)(m >> 8) * cp1 + (long)(m & 255) * 256 +
                   (long)(n >> 8) * cp3 + (n & 255);
        if (OUTMODE == 2)
          ((float*)Cptr)[off] = v;
        else
          ((f16*)Cptr)[off] = (f16)v;
      }
    }
  }
}

// ---------------- fused S = QK^T/16 -> softmax -> PV per (bc, h, 64-q tile) ----------------
__global__ __launch_bounds__(256) void attn_fused(const f16* __restrict__ Qw,
                                                  const f16* __restrict__ Kw,
                                                  const f16* __restrict__ Vw,
                                                  f16* __restrict__ Ow) {
  __shared__ f16 Ps[64 * 264];      // Q tile, then P tile (padded stride 264)
  __shared__ f16 Bs[2][256 * 32];   // K/V B-tiles (16KB each)
  const int tid = threadIdx.x;
  const int lane = tid & 63, wid = tid >> 6;
  const int l15 = lane & 15, lg = lane >> 4;
  const int qt = blockIdx.x, h = blockIdx.y, bc = blockIdx.z;
  const long hb = (long)bc * 524288 + (long)h * 65536;
  const int q0 = qt * 64;
  const f16* Qh = Qw + hb;
  const f16* Kh = Kw + hb;
  const f16* Vh = Vw + hb;

  // stage Q tile (64x256) into Ps with padded stride (reg-staged: padding
  // is incompatible with global_load_lds)
#pragma unroll
  for (int r = 0; r < 8; ++r) {
    int ci = r * 256 + tid;
    int row = ci >> 5;
    int c8 = ci & 31;
    f16x8 v = *(const f16x8*)(Qh + (long)(q0 + row) * 256 + c8 * 8);
    *(f16x8*)(&Ps[row * 264 + c8 * 8]) = v;
  }

  auto stageB = [&](const f16* src, int buf, int kt) {
#pragma unroll
    for (int r = 0; r < 4; ++r) {
      int flat = r * 4096 + tid * 16;
      int row = flat >> 6;
      int kk = kt * 32 + ((flat & 63) >> 1);
      gload16(src + (long)row * 256 + kk, (char*)(&Bs[buf][0]) + flat);
    }
  };

  f32x4 acc[16] = {};
  stageB(Kh, 0, 0);
  for (int t = 0; t < 8; ++t) {
    __syncthreads();
    if (t < 7) stageB(Kh, (t + 1) & 1, t + 1);
    f16x8 a = *(const f16x8*)(&Ps[(wid * 16 + l15) * 264 + t * 32 + lg * 8]);
    const f16* bs = &Bs[t & 1][0];
#pragma unroll
    for (int j = 0; j < 16; ++j) {
      f16x8 b = *(const f16x8*)(bs + (j * 16 + l15) * 32 + lg * 8);
      acc[j] = __builtin_amdgcn_mfma_f32_16x16x32_f16(a, b, acc[j], 0, 0, 0);
    }
  }

  // softmax over 256 cols; scale 1/16 folded into exp2 argument.
  // Row r of the wave's strip lives in lanes with lg = r/4, reg j = r%4.
  const float SCL = 0.0625f * 1.44269504089f;
  float inv[4];
#pragma unroll
  for (int j = 0; j < 4; ++j) {
    float m_ = acc[0][j];
#pragma unroll
    for (int f = 1; f < 16; ++f) m_ = fmaxf(m_, acc[f][j]);
#pragma unroll
    for (int off = 1; off < 16; off <<= 1) m_ = fmaxf(m_, __shfl_xor(m_, off, 64));
    float s_ = 0.f;
#pragma unroll
    for (int f = 0; f < 16; ++f) {
      float e = __builtin_exp2f((acc[f][j] - m_) * SCL);
      acc[f][j] = e;
      s_ += e;
    }
#pragma unroll
    for (int off = 1; off < 16; off <<= 1) s_ += __shfl_xor(s_, off, 64);
    inv[j] = 1.f / s_;
  }
  // write P (f16) into Ps; rows are wave-local so no extra barrier needed
#pragma unroll
  for (int f = 0; f < 16; ++f)
#pragma unroll
    for (int j = 0; j < 4; ++j)
      Ps[(wid * 16 + lg * 4 + j) * 264 + f * 16 + l15] = (f16)(acc[f][j] * inv[j]);

  __syncthreads();  // everyone done reading K tiles from Bs

  f32x4 oacc[16] = {};
  stageB(Vh, 0, 0);
  for (int t = 0; t < 8; ++t) {
    __syncthreads();
    if (t < 7) stageB(Vh, (t + 1) & 1, t + 1);
    f16x8 a = *(const f16x8*)(&Ps[(wid * 16 + l15) * 264 + t * 32 + lg * 8]);
    const f16* bs = &Bs[t & 1][0];
#pragma unroll
    for (int j = 0; j < 16; ++j) {
      f16x8 b = *(const f16x8*)(bs + (j * 16 + l15) * 32 + lg * 8);
      oacc[j] = __builtin_amdgcn_mfma_f32_16x16x32_f16(a, b, oacc[j], 0, 0, 0);
    }
  }

  // write O tile; aliases the Q region (each (bc,h,q-range) is touched only
  // by this block, and its Q reads completed above)
#pragma unroll
  for (int f = 0; f < 16; ++f)
#pragma unroll
    for (int j = 0; j < 4; ++j) {
      int q = q0 + wid * 16 + lg * 4 + j;
      int d = f * 16 + l15;
      Ow[hb + (long)q * 256 + d] = (f16)(oacc[f][j]);
    }
}

// ---------------- launch ----------------
// ws layout (bytes):
//   xb    @ 0         8388608   fp16 x            [16384][256]
//   WqT   @ 8388608   1048576   [2048][256] permuted-transposed
//   WkT   @ 9437184   1048576
//   WvT   @ 10485760  1048576
//   WoT   @ 11534336  1048576   [256][2048] permuted-transposed
//   bqp   @ 12582912  8192      fp32 permuted biases
//   bkp   @ 12591104  8192
//   bvp   @ 12599296  8192
//   Q     @ 12607488  67108864  [bc][h][q][d]  (attn_out overwrites in place)
//   K     @ +67108864 67108864  [bc][h][q][d]
//   VT    @ +2x...    67108864  [bc][h][d][q]
extern "C" void kernel_launch(void* const* d_in, const int* in_sizes, int n_in,
                              void* d_out, int out_size, void* d_ws,
                              size_t ws_size, hipStream_t stream) {
  const float* x = (const float*)d_in[0];
  const float* Wq = (const float*)d_in[1];
  const float* bq = (const float*)d_in[2];
  const float* Wk = (const float*)d_in[3];
  const float* bk = (const float*)d_in[4];
  const float* Wv = (const float*)d_in[5];
  const float* bv = (const float*)d_in[6];
  const float* Wo = (const float*)d_in[7];
  const float* bo = (const float*)d_in[8];

  char* ws = (char*)d_ws;
  f16* xb = (f16*)(ws + 0);
  f16* WqT = (f16*)(ws + 8388608);
  f16* WkT = (f16*)(ws + 9437184);
  f16* WvT = (f16*)(ws + 10485760);
  f16* WoT = (f16*)(ws + 11534336);
  float* bqp = (float*)(ws + 12582912);
  float* bkp = (float*)(ws + 12591104);
  float* bvp = (float*)(ws + 12599296);
  f16* Qws = (f16*)(ws + 12607488);
  f16* Kws = (f16*)(ws + 12607488 + 67108864L);
  f16* VTs = (f16*)(ws + 12607488 + 2L * 67108864L);
  if (ws_size < 12607488ull + 3ull * 67108864ull) return;  // need ~204MB scratch

  prep_x<<<4096, 256, 0, stream>>>(x, xb);
  prep_w<<<2048, 256, 0, stream>>>(Wq, Wk, Wv, Wo, bq, bk, bv, WqT, WkT, WvT,
                                   WoT, bqp, bkp, bvp);

  // Q, K projections: M=16384 (tokens), N=2048 (n'=h*256+d), K=256
  gemm128<0><<<dim3(16, 128), 256, 0, stream>>>(xb, WqT, bqp, Qws, 256, 65536,
                                                0, 256, 524288L, 65536L);
  gemm128<0><<<dim3(16, 128), 256, 0, stream>>>(xb, WkT, bkp, Kws, 256, 65536,
                                                0, 256, 524288L, 65536L);
  // V projection, operands swapped -> writes V^T per head: M=2048, N=16384
  gemm128<1><<<dim3(128, 16), 256, 0, stream>>>(WvT, xb, bvp, VTs, 256, 65536,
                                                0, 256, 65536L, 524288L);

  attn_fused<<<dim3(4, 8, 64), 256, 0, stream>>>(Qws, Kws, VTs, Qws);

  // output projection: M=16384, N=256, K=2048 (head-blocked A), fp32 out + bo
  gemm128<2><<<dim3(2, 128), 256, 0, stream>>>(Qws, WoT, bo, d_out, 2048,
                                               524288, 65536, 2048, 65536L, 0L);
}

// Round 2
// 237.455 us; speedup vs baseline: 1.1062x; 1.1062x over previous
//
#include <hip/hip_runtime.h>
#include <hip/hip_fp16.h>

typedef _Float16 f16;
typedef _Float16 f16x8 __attribute__((ext_vector_type(8)));
typedef _Float16 f16x4 __attribute__((ext_vector_type(4)));
typedef float f32x4 __attribute__((ext_vector_type(4)));

#define GLB(p) ((const __attribute__((address_space(1))) void*)(p))
#define LDSP(p) ((__attribute__((address_space(3))) void*)(p))

__device__ __forceinline__ void gload16(const void* g, void* l) {
  __builtin_amdgcn_global_load_lds(GLB(g), LDSP(l), 16, 0, 0);
}

// ---------------- prep ----------------
__global__ __launch_bounds__(256) void prep_x(const float* __restrict__ x,
                                              f16* __restrict__ xb) {
  int i = (blockIdx.x * 256 + threadIdx.x) * 4;
  float4 v = *(const float4*)(x + i);
  f16x4 o = {(f16)v.x, (f16)v.y, (f16)v.z, (f16)v.w};
  *(f16x4*)(xb + i) = o;
}

// WT'[n'][c] = W[c][(n'&255)*8 + (n'>>8)]   (n' = h*256+d, src n = d*8+h)
// WoT'[dm][n'] = Wo[(d*8+h)*256 + dm]
__global__ __launch_bounds__(256) void prep_w(
    const float* __restrict__ Wq, const float* __restrict__ Wk,
    const float* __restrict__ Wv, const float* __restrict__ Wo,
    const float* __restrict__ bq, const float* __restrict__ bk,
    const float* __restrict__ bv,
    f16* __restrict__ WqT, f16* __restrict__ WkT, f16* __restrict__ WvT,
    f16* __restrict__ WoT, float* __restrict__ bqp, float* __restrict__ bkp,
    float* __restrict__ bvp) {
  int i = blockIdx.x * 256 + threadIdx.x;  // 0..524287
  {
    int np = i >> 8, c = i & 255;
    int src = c * 2048 + (np & 255) * 8 + (np >> 8);
    WqT[i] = (f16)Wq[src];
    WkT[i] = (f16)Wk[src];
    WvT[i] = (f16)Wv[src];
  }
  {
    int dm = i >> 11, np = i & 2047;
    WoT[i] = (f16)Wo[((np & 255) * 8 + (np >> 8)) * 256 + dm];
  }
  if (i < 2048) {
    int src = (i & 255) * 8 + (i >> 8);
    bqp[i] = bq[src];
    bkp[i] = bk[src];
    bvp[i] = bv[src];
  }
}

// ---------------- generic 128x128 fp16 GEMM, K-innermost operands ----------------
// A(m,k) elem = (m>>8)*aq1 + (m&255)*256 + (k>>8)*aq3 + (k&255)
// B(n,k) elem = n*ldb + k
// C(m,n) elem = (m>>8)*cp1 + (m&255)*256 + (n>>8)*cp3 + (n&255)
// OUTMODE: 0 = f16 out + col bias, 1 = f16 out + row bias, 2 = f32 out + col bias
template <int OUTMODE>
__global__ __launch_bounds__(256) void gemm128(
    const f16* __restrict__ A, const f16* __restrict__ B,
    const float* __restrict__ bias, void* __restrict__ Cptr, int K, int aq1,
    int aq3, int ldb, long cp1, long cp3) {
  __shared__ f16 As[2][128 * 32];
  __shared__ f16 Bs[2][128 * 32];
  const int tid = threadIdx.x;
  const int m0 = blockIdx.y * 128;
  const int n0 = blockIdx.x * 128;
  const int lane = tid & 63, wid = tid >> 6;
  const int l15 = lane & 15, lg = lane >> 4;
  const int wm = (wid >> 1) * 64, wn = (wid & 1) * 64;

  f32x4 acc[4][4] = {};

  auto stage = [&](int buf, int kt) {
    int k0 = kt * 32;
#pragma unroll
    for (int r = 0; r < 2; ++r) {
      int flat = r * 4096 + tid * 16;  // byte offset within 8KB tile
      int row = flat >> 6;             // 64B per row
      int kk = k0 + ((flat & 63) >> 1);
      int m = m0 + row;
      gload16(A + (long)(m >> 8) * aq1 + (long)(m & 255) * 256 +
                  (long)(kk >> 8) * aq3 + (kk & 255),
              (char*)(&As[buf][0]) + flat);
      int n = n0 + row;
      gload16(B + (long)n * ldb + kk, (char*)(&Bs[buf][0]) + flat);
    }
  };

  const int T = K >> 5;
  stage(0, 0);
  for (int t = 0; t < T; ++t) {
    __syncthreads();  // staged buf[t&1] visible; all reads of buf[(t+1)&1] done
    if (t + 1 < T) stage((t + 1) & 1, t + 1);
    const f16* as = &As[t & 1][0];
    const f16* bs = &Bs[t & 1][0];
    f16x8 af[4], bf[4];
#pragma unroll
    for (int i = 0; i < 4; ++i)
      af[i] = *(const f16x8*)(as + (wm + i * 16 + l15) * 32 + lg * 8);
#pragma unroll
    for (int j = 0; j < 4; ++j)
      bf[j] = *(const f16x8*)(bs + (wn + j * 16 + l15) * 32 + lg * 8);
#pragma unroll
    for (int i = 0; i < 4; ++i)
#pragma unroll
      for (int j = 0; j < 4; ++j)
        acc[i][j] =
            __builtin_amdgcn_mfma_f32_16x16x32_f16(af[i], bf[j], acc[i][j], 0, 0, 0);
  }

#pragma unroll
  for (int i = 0; i < 4; ++i) {
#pragma unroll
    for (int j = 0; j < 4; ++j) {
#pragma unroll
      for (int jj = 0; jj < 4; ++jj) {
        int m = m0 + wm + i * 16 + lg * 4 + jj;
        int n = n0 + wn + j * 16 + l15;
        float v = acc[i][j][jj];
        v += (OUTMODE == 1) ? bias[m] : bias[n];
        long off = (long)(m >> 8) * cp1 + (long)(m & 255) * 256 +
                   (long)(n >> 8) * cp3 + (n & 255);
        if (OUTMODE == 2)
          ((float*)Cptr)[off] = v;
        else
          ((f16*)Cptr)[off] = (f16)v;
      }
    }
  }
}

// ---------------- fused attention: one block per (bc,h), q-tile = 256 ----------------
// 512 threads = 8 waves; wave w owns q rows [w*32, w*32+32).
// LDS (160 KiB exactly):
//   phase A: Qt[2][16KB] @ 0,  Kt[2][16KB] @ 32768        (within P region)
//   phase B: P  [256][256] f16 swizzled @ 0 (128KB),  Vt[2][16KB] @ 131072
__global__ __launch_bounds__(512, 2) void attn_fused2(const f16* __restrict__ Qw,
                                                      const f16* __restrict__ Kw,
                                                      const f16* __restrict__ Vw,
                                                      f16* __restrict__ Ow) {
  __shared__ __align__(16) char smem[163840];
  const int tid = threadIdx.x;
  const int lane = tid & 63, wid = tid >> 6;
  const int l15 = lane & 15, lg = lane >> 4;
  const int h = blockIdx.x, bc = blockIdx.y;
  const long hb = (long)bc * 524288 + (long)h * 65536;
  const f16* Qh = Qw + hb;
  const f16* Kh = Kw + hb;
  const f16* Vh = Vw + hb;  // V^T per head: [d][kq]
  const int w32 = wid * 32;

  // stage a [256 rows][32 k] f16 tile (16KB) with source-side swizzle so that
  // physical byte = row*64 + (colbytes ^ (((row>>1)&3)<<4)); LDS dest linear.
  auto stageT = [&](const f16* src, char* dst) {
#pragma unroll
    for (int r = 0; r < 2; ++r) {
      int flat = r * 8192 + tid * 16;
      int row = flat >> 6;
      int kk = ((flat ^ (((row >> 1) & 3) << 4)) & 63) >> 1;
      gload16(src + (long)row * 256 + kk, dst + flat);
    }
  };
  // swizzled fragment read from a [256][32] tile: logical (row, k-bytes koff)
  auto ldfrag = [&](const char* base, int row, int koff) -> f16x8 {
    return *(const f16x8*)(base + row * 64 + (koff ^ (((row >> 1) & 3) << 4)));
  };

  // ---------- phase A: S = Q K^T  (per wave: 32 q rows x 256 cols) ----------
  f32x4 acc[2][16] = {};
  stageT(Qh + 0 * 32, smem + 0);
  stageT(Kh + 0 * 32, smem + 32768);
  for (int t = 0; t < 8; ++t) {
    __syncthreads();
    if (t < 7) {
      stageT(Qh + (t + 1) * 32, smem + ((t + 1) & 1) * 16384);
      stageT(Kh + (t + 1) * 32, smem + 32768 + ((t + 1) & 1) * 16384);
    }
    const char* as = smem + (t & 1) * 16384;
    const char* bs = smem + 32768 + (t & 1) * 16384;
    f16x8 af[2];
#pragma unroll
    for (int i = 0; i < 2; ++i) af[i] = ldfrag(as, w32 + i * 16 + l15, lg * 16);
#pragma unroll
    for (int j = 0; j < 16; ++j) {
      f16x8 b = ldfrag(bs, j * 16 + l15, lg * 16);
#pragma unroll
      for (int i = 0; i < 2; ++i)
        acc[i][j] = __builtin_amdgcn_mfma_f32_16x16x32_f16(af[i], b, acc[i][j], 0, 0, 0);
    }
  }

  // prefetch V tile 0 into its own region (overlaps softmax)
  stageT(Vh + 0 * 32, smem + 131072);

  // ---------- softmax over 256 cols (rows are wave-local) ----------
  // S[q=w32+i*16+lg*4+jj][n=j*16+l15] lives in acc[i][j][jj]
  const float SCL = 0.0625f * 1.44269504089f;
  float inv[2][4];
#pragma unroll
  for (int i = 0; i < 2; ++i) {
#pragma unroll
    for (int jj = 0; jj < 4; ++jj) {
      float m_ = acc[i][0][jj];
#pragma unroll
      for (int f = 1; f < 16; ++f) m_ = fmaxf(m_, acc[i][f][jj]);
#pragma unroll
      for (int off = 1; off < 16; off <<= 1) m_ = fmaxf(m_, __shfl_xor(m_, off, 64));
      float s_ = 0.f;
#pragma unroll
      for (int f = 0; f < 16; ++f) {
        float e = __builtin_exp2f((acc[i][f][jj] - m_) * SCL);
        acc[i][f][jj] = e;
        s_ += e;
      }
#pragma unroll
      for (int off = 1; off < 16; off <<= 1) s_ += __shfl_xor(s_, off, 64);
      inv[i][jj] = 1.f / s_;
    }
  }

  __syncthreads();  // all waves done reading Q/K tiles (P overwrites them)

  // write P [256][256] f16, swizzled: byte = (row*512 + col*2) ^ ((row&7)<<4)
#pragma unroll
  for (int i = 0; i < 2; ++i)
#pragma unroll
    for (int f = 0; f < 16; ++f)
#pragma unroll
      for (int jj = 0; jj < 4; ++jj) {
        int row = w32 + i * 16 + lg * 4 + jj;
        int col = f * 16 + l15;
        int byte = (row * 512 + col * 2) ^ ((row & 7) << 4);
        *(f16*)(smem + byte) = (f16)(acc[i][f][jj] * inv[i][jj]);
      }

  // ---------- phase B: O = P V  (B operand = V^T tiles) ----------
  f32x4 oacc[2][16] = {};
  for (int t = 0; t < 8; ++t) {
    __syncthreads();  // t=0: P writes + V tile0 visible
    if (t < 7) stageT(Vh + (t + 1) * 32, smem + 131072 + ((t + 1) & 1) * 16384);
    const char* vb = smem + 131072 + (t & 1) * 16384;
    f16x8 pf[2];
#pragma unroll
    for (int i = 0; i < 2; ++i) {
      int row = w32 + i * 16 + l15;
      pf[i] = *(const f16x8*)(smem + ((row * 512 + t * 64 + lg * 16) ^ ((row & 7) << 4)));
    }
#pragma unroll
    for (int j = 0; j < 16; ++j) {
      f16x8 b = ldfrag(vb, j * 16 + l15, lg * 16);
#pragma unroll
      for (int i = 0; i < 2; ++i)
        oacc[i][j] = __builtin_amdgcn_mfma_f32_16x16x32_f16(pf[i], b, oacc[i][j], 0, 0, 0);
    }
  }

  // write O tile; aliases the Q region (this block's Q reads completed in phase A)
#pragma unroll
  for (int i = 0; i < 2; ++i)
#pragma unroll
    for (int f = 0; f < 16; ++f)
#pragma unroll
      for (int jj = 0; jj < 4; ++jj) {
        int q = w32 + i * 16 + lg * 4 + jj;
        int d = f * 16 + l15;
        Ow[hb + (long)q * 256 + d] = (f16)(oacc[i][f][jj]);
      }
}

// ---------------- launch ----------------
// ws layout (bytes):
//   xb    @ 0         8388608   fp16 x            [16384][256]
//   WqT   @ 8388608   1048576   [2048][256] permuted-transposed
//   WkT   @ 9437184   1048576
//   WvT   @ 10485760  1048576
//   WoT   @ 11534336  1048576   [256][2048] permuted-transposed
//   bqp   @ 12582912  8192      fp32 permuted biases
//   bkp   @ 12591104  8192
//   bvp   @ 12599296  8192
//   Q     @ 12607488  67108864  [bc][h][q][d]  (attn_out overwrites in place)
//   K     @ +67108864 67108864  [bc][h][q][d]
//   VT    @ +2x...    67108864  [bc][h][d][q]
extern "C" void kernel_launch(void* const* d_in, const int* in_sizes, int n_in,
                              void* d_out, int out_size, void* d_ws,
                              size_t ws_size, hipStream_t stream) {
  const float* x = (const float*)d_in[0];
  const float* Wq = (const float*)d_in[1];
  const float* bq = (const float*)d_in[2];
  const float* Wk = (const float*)d_in[3];
  const float* bk = (const float*)d_in[4];
  const float* Wv = (const float*)d_in[5];
  const float* bv = (const float*)d_in[6];
  const float* Wo = (const float*)d_in[7];
  const float* bo = (const float*)d_in[8];

  char* ws = (char*)d_ws;
  f16* xb = (f16*)(ws + 0);
  f16* WqT = (f16*)(ws + 8388608);
  f16* WkT = (f16*)(ws + 9437184);
  f16* WvT = (f16*)(ws + 10485760);
  f16* WoT = (f16*)(ws + 11534336);
  float* bqp = (float*)(ws + 12582912);
  float* bkp = (float*)(ws + 12591104);
  float* bvp = (float*)(ws + 12599296);
  f16* Qws = (f16*)(ws + 12607488);
  f16* Kws = (f16*)(ws + 12607488 + 67108864L);
  f16* VTs = (f16*)(ws + 12607488 + 2L * 67108864L);
  if (ws_size < 12607488ull + 3ull * 67108864ull) return;  // need ~204MB scratch

  prep_x<<<4096, 256, 0, stream>>>(x, xb);
  prep_w<<<2048, 256, 0, stream>>>(Wq, Wk, Wv, Wo, bq, bk, bv, WqT, WkT, WvT,
                                   WoT, bqp, bkp, bvp);

  // Q, K projections: M=16384 (tokens), N=2048 (n'=h*256+d), K=256
  gemm128<0><<<dim3(16, 128), 256, 0, stream>>>(xb, WqT, bqp, Qws, 256, 65536,
                                                0, 256, 524288L, 65536L);
  gemm128<0><<<dim3(16, 128), 256, 0, stream>>>(xb, WkT, bkp, Kws, 256, 65536,
                                                0, 256, 524288L, 65536L);
  // V projection, operands swapped -> writes V^T per head: M=2048, N=16384
  gemm128<1><<<dim3(128, 16), 256, 0, stream>>>(WvT, xb, bvp, VTs, 256, 65536,
                                                0, 256, 65536L, 524288L);

  attn_fused2<<<dim3(8, 64), 512, 0, stream>>>(Qws, Kws, VTs, Qws);

  // output projection: M=16384, N=256, K=2048 (head-blocked A), fp32 out + bo
  gemm128<2><<<dim3(2, 128), 256, 0, stream>>>(Qws, WoT, bo, d_out, 2048,
                                               524288, 65536, 2048, 65536L, 0L);
}